// Round 1
// baseline (595.679 us; speedup 1.0000x reference)
//
#include <hip/hip_runtime.h>
#include <hip/hip_bf16.h>

#define B_DIM 64
#define T_DIM 2048
#define D_DIM 512
#define U_DIM 512

#define TM 128
#define TN 128
#define BK 64
#define LDSK 72   // BK + 8 pad (bank spread), keeps 16B alignment (144 B rows)

typedef __bf16 bf16x8 __attribute__((ext_vector_type(8)));
typedef float  f32x4  __attribute__((ext_vector_type(4)));

// ---------------------------------------------------------------------------
// W1 [D][U] fp32  ->  w1t [U][D] bf16   (tiny: 1 MiB read)
// ---------------------------------------------------------------------------
__global__ void w1t_kernel(const float* __restrict__ W1w, __bf16* __restrict__ w1t) {
    int idx = blockIdx.x * 256 + threadIdx.x;     // 262144 total
    int d = idx >> 9;
    int u = idx & 511;
    w1t[u * D_DIM + d] = (__bf16)W1w[idx];
}

// ---------------------------------------------------------------------------
// hp[b][u] = W1_b[u] + W2_b[u] + hidden[b,:] @ W2[:,u]   (fp32, tiny)
// ---------------------------------------------------------------------------
__global__ void hproj_kernel(const float* __restrict__ hidden,
                             const float* __restrict__ W2w,
                             const float* __restrict__ W2b,
                             const float* __restrict__ W1b,
                             float* __restrict__ hp) {
    int b = blockIdx.x;
    int u = threadIdx.x;                           // 512 threads
    float acc = W2b[u] + W1b[u];
    const float* hrow = hidden + b * D_DIM;
    #pragma unroll 8
    for (int d = 0; d < D_DIM; ++d)
        acc = fmaf(hrow[d], W2w[d * U_DIM + u], acc);
    hp[b * U_DIM + u] = acc;
}

// ---------------------------------------------------------------------------
// scores[b*T+t] += sum_u tanh(features[b,t,:]@W1[:,u] + hp[b,u]) * Vw[u]
// Fused bf16-MFMA GEMM, tile 128(M) x 128(N), K=512 loop, BK=64.
// Grid: (M/128 = 1024, U/128 = 4), block 256 (4 waves, 2x2 of 64x64).
// ---------------------------------------------------------------------------
__global__ __launch_bounds__(256) void score_kernel(
        const float*  __restrict__ features,
        const __bf16* __restrict__ w1t,
        const float*  __restrict__ hp,
        const float*  __restrict__ Vw,
        float*        __restrict__ scores) {
    __shared__ __bf16 As[TM * LDSK];
    __shared__ __bf16 Bs[TN * LDSK];

    const int tid  = threadIdx.x;
    const int row0 = blockIdx.x * TM;          // global flattened (b,t) row base
    const int u0   = blockIdx.y * TN;
    const int b    = row0 >> 11;               // T=2048 rows per batch; tiles never straddle b

    const int srow  = tid >> 1;                // staging: 2 threads per row
    const int shalf = tid & 1;

    const int wave = tid >> 6;
    const int lane = tid & 63;
    const int wm   = wave & 1;                 // 2x2 wave grid over the 128x128 tile
    const int wn   = wave >> 1;
    const int l16  = lane & 15;
    const int quad = lane >> 4;

    f32x4 acc[4][4];
    #pragma unroll
    for (int i = 0; i < 4; ++i)
        #pragma unroll
        for (int j = 0; j < 4; ++j)
            acc[i][j] = (f32x4)0.0f;

    const float*  ag = features + (size_t)(row0 + srow) * D_DIM + shalf * 32;
    const __bf16* bg = w1t      + (size_t)(u0   + srow) * D_DIM + shalf * 32;

    for (int kb = 0; kb < D_DIM; kb += BK) {
        // ---- stage A: features 128x64 fp32 -> bf16 in LDS ----
        const float4* asrc = reinterpret_cast<const float4*>(ag + kb);
        #pragma unroll
        for (int j = 0; j < 4; ++j) {
            float4 v0 = asrc[2 * j];
            float4 v1 = asrc[2 * j + 1];
            bf16x8 w;
            w[0] = (__bf16)v0.x; w[1] = (__bf16)v0.y; w[2] = (__bf16)v0.z; w[3] = (__bf16)v0.w;
            w[4] = (__bf16)v1.x; w[5] = (__bf16)v1.y; w[6] = (__bf16)v1.z; w[7] = (__bf16)v1.w;
            *reinterpret_cast<bf16x8*>(&As[srow * LDSK + shalf * 32 + j * 8]) = w;
        }
        // ---- stage B: w1t 128x64 bf16 ----
        const bf16x8* bsrc = reinterpret_cast<const bf16x8*>(bg + kb);
        #pragma unroll
        for (int j = 0; j < 4; ++j)
            *reinterpret_cast<bf16x8*>(&Bs[srow * LDSK + shalf * 32 + j * 8]) = bsrc[j];

        __syncthreads();

        #pragma unroll
        for (int ks = 0; ks < 2; ++ks) {
            bf16x8 af[4], bfr[4];
            #pragma unroll
            for (int mt = 0; mt < 4; ++mt)
                af[mt] = *reinterpret_cast<const bf16x8*>(
                    &As[(wm * 64 + mt * 16 + l16) * LDSK + ks * 32 + quad * 8]);
            #pragma unroll
            for (int nt = 0; nt < 4; ++nt)
                bfr[nt] = *reinterpret_cast<const bf16x8*>(
                    &Bs[(wn * 64 + nt * 16 + l16) * LDSK + ks * 32 + quad * 8]);
            #pragma unroll
            for (int mt = 0; mt < 4; ++mt)
                #pragma unroll
                for (int nt = 0; nt < 4; ++nt)
                    acc[mt][nt] = __builtin_amdgcn_mfma_f32_16x16x32_bf16(
                        af[mt], bfr[nt], acc[mt][nt], 0, 0, 0);
        }
        __syncthreads();
    }

    // ---- epilogue: tanh(f_proj + hp) dot Vw over this block's 128 u's ----
    float hpv[4], vwv[4];
    #pragma unroll
    for (int nt = 0; nt < 4; ++nt) {
        int u = u0 + wn * 64 + nt * 16 + l16;   // C/D col = lane&15
        hpv[nt] = hp[b * U_DIM + u];
        vwv[nt] = Vw[u];
    }
    #pragma unroll
    for (int mt = 0; mt < 4; ++mt) {
        #pragma unroll
        for (int reg = 0; reg < 4; ++reg) {
            float s = 0.0f;
            #pragma unroll
            for (int nt = 0; nt < 4; ++nt) {
                float x = acc[mt][nt][reg] + hpv[nt];
                // tanh(x) = 1 - 2/(e^{2x}+1); e^{2x} = exp2(2.885390x). No inf/inf.
                float e = exp2f(x * 2.88539008f);
                float th = 1.0f - 2.0f * __builtin_amdgcn_rcpf(e + 1.0f);
                s = fmaf(th, vwv[nt], s);
            }
            // reduce over the 16 n-lanes of this quad
            s += __shfl_xor(s, 1);
            s += __shfl_xor(s, 2);
            s += __shfl_xor(s, 4);
            s += __shfl_xor(s, 8);
            if (l16 == 0) {
                int row = row0 + wm * 64 + mt * 16 + quad * 4 + reg;  // C/D row = quad*4+reg
                atomicAdd(&scores[row], s);
            }
        }
    }
}

// ---------------------------------------------------------------------------
// softmax over T per batch. 64 blocks x 256 threads, 8 elems/thread.
// ---------------------------------------------------------------------------
__global__ void softmax_kernel(const float* __restrict__ scores, float* __restrict__ attn) {
    int b = blockIdx.x;
    int tid = threadIdx.x;
    __shared__ float red[4], red2[4];

    float s[8];
    float m = -1e30f;
    #pragma unroll
    for (int i = 0; i < 8; ++i) {
        s[i] = scores[b * T_DIM + i * 256 + tid];
        m = fmaxf(m, s[i]);
    }
    #pragma unroll
    for (int off = 1; off < 64; off <<= 1) m = fmaxf(m, __shfl_xor(m, off));
    if ((tid & 63) == 0) red[tid >> 6] = m;
    __syncthreads();
    m = fmaxf(fmaxf(red[0], red[1]), fmaxf(red[2], red[3]));

    float e[8], sum = 0.0f;
    #pragma unroll
    for (int i = 0; i < 8; ++i) {
        e[i] = exp2f((s[i] - m) * 1.44269504f);
        sum += e[i];
    }
    #pragma unroll
    for (int off = 1; off < 64; off <<= 1) sum += __shfl_xor(sum, off);
    if ((tid & 63) == 0) red2[tid >> 6] = sum;
    __syncthreads();
    sum = red2[0] + red2[1] + red2[2] + red2[3];
    float inv = 1.0f / sum;
    #pragma unroll
    for (int i = 0; i < 8; ++i)
        attn[b * T_DIM + i * 256 + tid] = e[i] * inv;
}

// ---------------------------------------------------------------------------
// context[b][d] = sum_t attn[b][t] * features[b][t][d]   (fp32, HBM-bound)
// Grid (16 t-chunks, 64 b), block 128; thread owns one float4 column.
// ---------------------------------------------------------------------------
__global__ void context_kernel(const float* __restrict__ attn,
                               const float* __restrict__ features,
                               float* __restrict__ out) {
    int b  = blockIdx.y;
    int t0 = blockIdx.x * 128;
    int d4 = threadIdx.x;   // 0..127
    const float4* f = reinterpret_cast<const float4*>(features) + (size_t)b * T_DIM * 128;
    float4 acc = {0.f, 0.f, 0.f, 0.f};
    for (int i = 0; i < 128; ++i) {
        int t = t0 + i;
        float a = attn[b * T_DIM + t];
        float4 v = f[(size_t)t * 128 + d4];
        acc.x = fmaf(a, v.x, acc.x);
        acc.y = fmaf(a, v.y, acc.y);
        acc.z = fmaf(a, v.z, acc.z);
        acc.w = fmaf(a, v.w, acc.w);
    }
    float* o = out + b * D_DIM + d4 * 4;
    atomicAdd(o + 0, acc.x);
    atomicAdd(o + 1, acc.y);
    atomicAdd(o + 2, acc.z);
    atomicAdd(o + 3, acc.w);
}

// ---------------------------------------------------------------------------
extern "C" void kernel_launch(void* const* d_in, const int* in_sizes, int n_in,
                              void* d_out, int out_size, void* d_ws, size_t ws_size,
                              hipStream_t stream) {
    const float* features = (const float*)d_in[0];
    const float* hidden   = (const float*)d_in[1];
    const float* W1w      = (const float*)d_in[2];
    const float* W1b      = (const float*)d_in[3];
    const float* W2w      = (const float*)d_in[4];
    const float* W2b      = (const float*)d_in[5];
    const float* Vw       = (const float*)d_in[6];
    // V_b (d_in[7]) cancels in softmax — unused.

    char* ws = (char*)d_ws;
    __bf16* w1t   = (__bf16*)ws;                       // 512 KiB
    float*  scores = (float*)(ws + (512u << 10));      // 512 KiB
    float*  attn   = (float*)(ws + (1024u << 10));     // 512 KiB
    float*  hp     = (float*)(ws + (1536u << 10));     // 128 KiB

    hipMemsetAsync(scores, 0, B_DIM * T_DIM * sizeof(float), stream);
    hipMemsetAsync(d_out, 0, out_size * sizeof(float), stream);

    hipLaunchKernelGGL(w1t_kernel, dim3(1024), dim3(256), 0, stream, W1w, w1t);
    hipLaunchKernelGGL(hproj_kernel, dim3(B_DIM), dim3(512), 0, stream,
                       hidden, W2w, W2b, W1b, hp);
    hipLaunchKernelGGL(score_kernel, dim3(1024, 4), dim3(256), 0, stream,
                       features, w1t, hp, Vw, scores);
    hipLaunchKernelGGL(softmax_kernel, dim3(B_DIM), dim3(256), 0, stream, scores, attn);
    hipLaunchKernelGGL(context_kernel, dim3(16, B_DIM), dim3(128), 0, stream,
                       attn, features, (float*)d_out);
}

// Round 2
// 497.291 us; speedup vs baseline: 1.1978x; 1.1978x over previous
//
#include <hip/hip_runtime.h>
#include <hip/hip_bf16.h>

#define B_DIM 64
#define T_DIM 2048
#define D_DIM 512
#define U_DIM 512

typedef __bf16 bf16x8 __attribute__((ext_vector_type(8)));
typedef float  f32x4  __attribute__((ext_vector_type(4)));
typedef unsigned int u32;

// async global->LDS, 16B per lane (global_load_lds_dwordx4)
__device__ __forceinline__ void gl_lds16(const __bf16* g, __bf16* l) {
    __builtin_amdgcn_global_load_lds(
        (const __attribute__((address_space(1))) u32*)g,
        (__attribute__((address_space(3))) u32*)l,
        16, 0, 0);
}

// ---------------------------------------------------------------------------
// W1 [D][U] fp32 -> w1s bf16 in K-plane layout: w1s[kb2][u][k], kb2=d>>5, k=d&31.
// offset = kb2*16384 + u*32 + k. Grid (16,8), block 256. LDS tile transpose.
// ---------------------------------------------------------------------------
__global__ void w1s_kernel(const float* __restrict__ W1w, __bf16* __restrict__ w1s) {
    __shared__ float tile[64][33];
    const int tid = threadIdx.x;
    const int kb2 = blockIdx.x;          // 32-d block
    const int ub  = blockIdx.y;          // 64-u block
    #pragma unroll
    for (int i = 0; i < 8; ++i) {
        int k = i * 4 + (tid >> 6);                 // 0..31
        int u = tid & 63;
        tile[u][k] = W1w[(kb2 * 32 + k) * U_DIM + ub * 64 + u];
    }
    __syncthreads();
    int u_l = tid >> 2;                  // 0..63
    int kp  = (tid & 3) * 8;             // 0,8,16,24
    bf16x8 w;
    #pragma unroll
    for (int j = 0; j < 8; ++j) w[j] = (__bf16)tile[u_l][kp + j];
    *reinterpret_cast<bf16x8*>(&w1s[kb2 * 16384 + (ub * 64 + u_l) * 32 + kp]) = w;
}

// ---------------------------------------------------------------------------
// hp[b][u] = W1_b[u] + W2_b[u] + hidden[b,:] @ W2[:,u]. Grid (B,2), block 256.
// ---------------------------------------------------------------------------
__global__ void hproj_kernel(const float* __restrict__ hidden,
                             const float* __restrict__ W2w,
                             const float* __restrict__ W2b,
                             const float* __restrict__ W1b,
                             float* __restrict__ hp) {
    int b = blockIdx.x;
    int u = blockIdx.y * 256 + threadIdx.x;
    float acc = W2b[u] + W1b[u];
    const float* hrow = hidden + b * D_DIM;
    #pragma unroll 8
    for (int d = 0; d < D_DIM; ++d)
        acc = fmaf(hrow[d], W2w[d * U_DIM + u], acc);
    hp[b * U_DIM + u] = acc;
}

// ---------------------------------------------------------------------------
// scores[row] = sum_{u<512} tanh(features[row,:]@W1[:,u] + hp[b,u]) * Vw[u]
// One block = 64 rows x ALL 512 u. features read ONCE. BK=64 via two 32-K
// LDS planes (unpadded 64B row stride = bank-even). B staged async.
// Grid 2048, block 256 (4 waves, each: 64 rows x 128 u).
// ---------------------------------------------------------------------------
__global__ __launch_bounds__(256, 2) void score_kernel(
        const float*  __restrict__ features,
        const __bf16* __restrict__ w1s,
        const float*  __restrict__ hp,
        const float*  __restrict__ Vw,
        float*        __restrict__ scores) {
    __shared__ __align__(16) __bf16 As0[64 * 32];
    __shared__ __align__(16) __bf16 As1[64 * 32];
    __shared__ __align__(16) __bf16 Bs0[512 * 32];
    __shared__ __align__(16) __bf16 Bs1[512 * 32];
    __shared__ float red[4 * 64];

    const int tid  = threadIdx.x;
    const int row0 = blockIdx.x * 64;          // flattened (b,t) base
    const int b    = row0 >> 11;

    const int wn   = tid >> 6;                 // wave 0..3 -> u window wn*128
    const int lane = tid & 63;
    const int l16  = lane & 15;
    const int quad = lane >> 4;

    const int arow = tid >> 2;                 // staging: 4 threads/row
    const int aq   = tid & 3;

    f32x4 acc[4][8];
    #pragma unroll
    for (int i = 0; i < 4; ++i)
        #pragma unroll
        for (int j = 0; j < 8; ++j)
            acc[i][j] = (f32x4)0.0f;

    const float* ag = features + (size_t)(row0 + arow) * D_DIM + aq * 8;

    for (int ko = 0; ko < 8; ++ko) {           // 8 x BK=64
        // ---- B: two 32-K planes, contiguous async copy (32 KiB each) ----
        const __bf16* bsrc0 = w1s + (2 * ko) * 16384 + tid * 8;
        const __bf16* bsrc1 = w1s + (2 * ko + 1) * 16384 + tid * 8;
        #pragma unroll
        for (int c = 0; c < 8; ++c) {
            gl_lds16(bsrc0 + c * 2048, Bs0 + c * 2048 + tid * 8);
            gl_lds16(bsrc1 + c * 2048, Bs1 + c * 2048 + tid * 8);
        }
        // ---- A: 64 rows x 64 k fp32 -> bf16, split across the two planes ----
        {
            const float4* s0 = reinterpret_cast<const float4*>(ag + ko * 64);
            const float4* s1 = reinterpret_cast<const float4*>(ag + ko * 64 + 32);
            float4 v0 = s0[0], v1 = s0[1];
            float4 v2 = s1[0], v3 = s1[1];
            bf16x8 w0, w1;
            w0[0] = (__bf16)v0.x; w0[1] = (__bf16)v0.y; w0[2] = (__bf16)v0.z; w0[3] = (__bf16)v0.w;
            w0[4] = (__bf16)v1.x; w0[5] = (__bf16)v1.y; w0[6] = (__bf16)v1.z; w0[7] = (__bf16)v1.w;
            w1[0] = (__bf16)v2.x; w1[1] = (__bf16)v2.y; w1[2] = (__bf16)v2.z; w1[3] = (__bf16)v2.w;
            w1[4] = (__bf16)v3.x; w1[5] = (__bf16)v3.y; w1[6] = (__bf16)v3.z; w1[7] = (__bf16)v3.w;
            *reinterpret_cast<bf16x8*>(&As0[arow * 32 + aq * 8]) = w0;
            *reinterpret_cast<bf16x8*>(&As1[arow * 32 + aq * 8]) = w1;
        }
        __syncthreads();

        // ---- MFMA: plane 0 then plane 1 ----
        #pragma unroll
        for (int ks = 0; ks < 2; ++ks) {
            const __bf16* Ap = ks ? As1 : As0;
            const __bf16* Bp = ks ? Bs1 : Bs0;
            bf16x8 af[4], bfr[8];
            #pragma unroll
            for (int mt = 0; mt < 4; ++mt)
                af[mt] = *reinterpret_cast<const bf16x8*>(
                    &Ap[(mt * 16 + l16) * 32 + quad * 8]);
            #pragma unroll
            for (int nt = 0; nt < 8; ++nt)
                bfr[nt] = *reinterpret_cast<const bf16x8*>(
                    &Bp[(wn * 128 + nt * 16 + l16) * 32 + quad * 8]);
            #pragma unroll
            for (int mt = 0; mt < 4; ++mt)
                #pragma unroll
                for (int nt = 0; nt < 8; ++nt)
                    acc[mt][nt] = __builtin_amdgcn_mfma_f32_16x16x32_bf16(
                        af[mt], bfr[nt], acc[mt][nt], 0, 0, 0);
        }
        __syncthreads();
    }

    // ---- epilogue: tanh(f_proj + hp) . Vw, reduce over u ----
    float hpv[8], vwv[8];
    #pragma unroll
    for (int nt = 0; nt < 8; ++nt) {
        int u = wn * 128 + nt * 16 + l16;       // C/D col = lane&15
        hpv[nt] = hp[b * U_DIM + u];
        vwv[nt] = Vw[u];
    }
    #pragma unroll
    for (int mt = 0; mt < 4; ++mt) {
        #pragma unroll
        for (int reg = 0; reg < 4; ++reg) {
            float s = 0.0f;
            #pragma unroll
            for (int nt = 0; nt < 8; ++nt) {
                float x = acc[mt][nt][reg] + hpv[nt];
                float e = exp2f(x * 2.88539008f);           // e^{2x}
                float th = 1.0f - 2.0f * __builtin_amdgcn_rcpf(e + 1.0f);
                s = fmaf(th, vwv[nt], s);
            }
            s += __shfl_xor(s, 1);
            s += __shfl_xor(s, 2);
            s += __shfl_xor(s, 4);
            s += __shfl_xor(s, 8);
            if (l16 == 0)
                red[wn * 64 + mt * 16 + quad * 4 + reg] = s;  // C/D row = quad*4+reg
        }
    }
    __syncthreads();
    if (tid < 64)
        scores[row0 + tid] = red[tid] + red[64 + tid] + red[128 + tid] + red[192 + tid];
}

// ---------------------------------------------------------------------------
// softmax over T per batch. 64 blocks x 256 threads, 8 elems/thread.
// ---------------------------------------------------------------------------
__global__ void softmax_kernel(const float* __restrict__ scores, float* __restrict__ attn) {
    int b = blockIdx.x;
    int tid = threadIdx.x;
    __shared__ float red[4], red2[4];

    float s[8];
    float m = -1e30f;
    #pragma unroll
    for (int i = 0; i < 8; ++i) {
        s[i] = scores[b * T_DIM + i * 256 + tid];
        m = fmaxf(m, s[i]);
    }
    #pragma unroll
    for (int off = 1; off < 64; off <<= 1) m = fmaxf(m, __shfl_xor(m, off));
    if ((tid & 63) == 0) red[tid >> 6] = m;
    __syncthreads();
    m = fmaxf(fmaxf(red[0], red[1]), fmaxf(red[2], red[3]));

    float e[8], sum = 0.0f;
    #pragma unroll
    for (int i = 0; i < 8; ++i) {
        e[i] = exp2f((s[i] - m) * 1.44269504f);
        sum += e[i];
    }
    #pragma unroll
    for (int off = 1; off < 64; off <<= 1) sum += __shfl_xor(sum, off);
    if ((tid & 63) == 0) red2[tid >> 6] = sum;
    __syncthreads();
    sum = red2[0] + red2[1] + red2[2] + red2[3];
    float inv = 1.0f / sum;
    #pragma unroll
    for (int i = 0; i < 8; ++i)
        attn[b * T_DIM + i * 256 + tid] = e[i] * inv;
}

// ---------------------------------------------------------------------------
// context[b][d] = sum_t attn[b][t] * features[b][t][d]
// Grid (4, 64), block 256: block owns (b, 32 float4 columns) for ALL T.
// 8 t-partitions per thread-group -> LDS reduce -> direct store (no atomics).
// ---------------------------------------------------------------------------
__global__ void context_kernel(const float* __restrict__ attn,
                               const float* __restrict__ features,
                               float* __restrict__ out) {
    __shared__ float4 red[256];
    const int tid = threadIdx.x;
    const int b   = blockIdx.y;
    const int d4  = (blockIdx.x << 5) + (tid & 31);   // float4 column 0..127
    const int tp  = tid >> 5;                          // 0..7

    const float4* f  = reinterpret_cast<const float4*>(features) + (size_t)b * T_DIM * 128;
    const float*  ar = attn + b * T_DIM;

    float4 acc = {0.f, 0.f, 0.f, 0.f};
    #pragma unroll 8
    for (int i = 0; i < 256; ++i) {
        int t = tp * 256 + i;
        float a = ar[t];
        float4 v = f[(size_t)t * 128 + d4];
        acc.x = fmaf(a, v.x, acc.x);
        acc.y = fmaf(a, v.y, acc.y);
        acc.z = fmaf(a, v.z, acc.z);
        acc.w = fmaf(a, v.w, acc.w);
    }
    red[tid] = acc;
    __syncthreads();
    if (tp == 0) {
        float4 s = red[tid];
        #pragma unroll
        for (int j = 1; j < 8; ++j) {
            float4 v = red[tid + 32 * j];
            s.x += v.x; s.y += v.y; s.z += v.z; s.w += v.w;
        }
        reinterpret_cast<float4*>(out)[b * 128 + d4] = s;
    }
}

// ---------------------------------------------------------------------------
extern "C" void kernel_launch(void* const* d_in, const int* in_sizes, int n_in,
                              void* d_out, int out_size, void* d_ws, size_t ws_size,
                              hipStream_t stream) {
    const float* features = (const float*)d_in[0];
    const float* hidden   = (const float*)d_in[1];
    const float* W1w      = (const float*)d_in[2];
    const float* W1b      = (const float*)d_in[3];
    const float* W2w      = (const float*)d_in[4];
    const float* W2b      = (const float*)d_in[5];
    const float* Vw       = (const float*)d_in[6];
    // V_b cancels in softmax — unused.

    char* ws = (char*)d_ws;
    __bf16* w1s    = (__bf16*)ws;                      // 512 KiB
    float*  scores = (float*)(ws + (512u << 10));      // 512 KiB
    float*  attn   = (float*)(ws + (1024u << 10));     // 512 KiB
    float*  hp     = (float*)(ws + (1536u << 10));     // 128 KiB

    hipLaunchKernelGGL(w1s_kernel, dim3(16, 8), dim3(256), 0, stream, W1w, w1s);
    hipLaunchKernelGGL(hproj_kernel, dim3(B_DIM, 2), dim3(256), 0, stream,
                       hidden, W2w, W2b, W1b, hp);
    hipLaunchKernelGGL(score_kernel, dim3(2048), dim3(256), 0, stream,
                       features, w1s, hp, Vw, scores);
    hipLaunchKernelGGL(softmax_kernel, dim3(B_DIM), dim3(256), 0, stream, scores, attn);
    hipLaunchKernelGGL(context_kernel, dim3(4, B_DIM), dim3(256), 0, stream,
                       attn, features, (float*)d_out);
}